// Round 2
// baseline (1336.889 us; speedup 1.0000x reference)
//
#include <hip/hip_runtime.h>
#include <cstdint>

typedef unsigned short u16;
typedef unsigned int   u32;
typedef __bf16 bf16x8 __attribute__((ext_vector_type(8)));
typedef float  f32x4  __attribute__((ext_vector_type(4)));

#define TOKENS 50176
#define DIMC   576
#define HOUT   3456
#define DHC    2304
#define NHEAD  18
#define NSEQ   196
#define NPAD   224
#define SCALE  0.17677669529663687f

// ---- helpers -------------------------------------------------------------
__device__ __forceinline__ u16 f2b(float f) {            // fp32 -> bf16 RNE
  union { float f; u32 u; } v; v.f = f;
  u32 u = v.u;
  return (u16)((u + 0x7fffu + ((u >> 16) & 1u)) >> 16);
}

__device__ __forceinline__ f32x4 mfma16(bf16x8 a, bf16x8 b, f32x4 c) {
  return __builtin_amdgcn_mfma_f32_16x16x32_bf16(a, b, c, 0, 0, 0);
}

typedef const __attribute__((address_space(1))) char gas_char;
typedef __attribute__((address_space(3))) char las_char;
// async global->LDS, 16B/lane; LDS dest = wave-uniform base + lane*16
__device__ __forceinline__ void gl2lds16(const void* g, void* l) {
  __builtin_amdgcn_global_load_lds((gas_char*)(uintptr_t)g,
                                   (las_char*)(u32)(uintptr_t)l, 16, 0, 0);
}

// ---- LayerNorm -> bf16 ---------------------------------------------------
__global__ __launch_bounds__(256) void ln_kernel(const float* __restrict__ x,
                                                 const float* __restrict__ w,
                                                 const float* __restrict__ bsh,
                                                 u16* __restrict__ xn) {
  int lane = threadIdx.x & 63;
  int tok  = blockIdx.x * 4 + (threadIdx.x >> 6);
  const float* xr = x + (size_t)tok * DIMC;
  float v[9]; float s = 0.f;
#pragma unroll
  for (int i = 0; i < 9; ++i) { v[i] = xr[lane + 64 * i]; s += v[i]; }
#pragma unroll
  for (int o = 32; o >= 1; o >>= 1) s += __shfl_xor(s, o, 64);
  float mu = s * (1.f / 576.f);
  float var = 0.f;
#pragma unroll
  for (int i = 0; i < 9; ++i) { float d = v[i] - mu; var += d * d; }
#pragma unroll
  for (int o = 32; o >= 1; o >>= 1) var += __shfl_xor(var, o, 64);
  float rs = rsqrtf(var * (1.f / 576.f) + 1e-5f);
  u16* xo = xn + (size_t)tok * DIMC;
#pragma unroll
  for (int i = 0; i < 9; ++i) {
    int c = lane + 64 * i;
    xo[c] = f2b((v[i] - mu) * rs * w[c] + bsh[c]);
  }
}

// ---- cast + transpose weights: src KxNn (fp32) -> dst Npad x K (bf16) ----
__global__ void transpose_cast(const float* __restrict__ src, u16* __restrict__ dst,
                               int K, int Nn, int Npad) {
  int idx = blockIdx.x * 256 + threadIdx.x;
  if (idx >= K * Npad) return;
  int k = idx / Npad, n = idx - k * Npad;
  dst[(size_t)n * K + k] = (n < Nn) ? f2b(src[(size_t)k * Nn + n]) : (u16)0;
}

// ---- expand attention bias gather: bfull[h][m][n] ------------------------
__global__ void bias_expand(const float* __restrict__ ab, const int* __restrict__ idxs,
                            float* __restrict__ bf, int off_stride) {
  int i = blockIdx.x * 256 + threadIdx.x;
  if (i >= NHEAD * NSEQ * NSEQ) return;
  int h = i / (NSEQ * NSEQ), mn = i - h * (NSEQ * NSEQ);
  bf[i] = ab[h * off_stride + idxs[mn]];
}

// ---- 128x128-tile bf16 MFMA GEMM, A (MxK) row-major, BT (NxK) row-major --
template <int KDIM, int NSTRIDE, int NREAL, bool OUT_BF16>
__global__ __launch_bounds__(256) void gemm_tn(const u16* __restrict__ A,
                                               const u16* __restrict__ BT,
                                               const float* __restrict__ bias,
                                               void* __restrict__ Cv) {
  __shared__ u16 a_sm[128 * 32];
  __shared__ u16 b_sm[128 * 32];
  const int tid = threadIdx.x;
  const int w = tid >> 6, lane = tid & 63;
  const int m0 = blockIdx.y * 128, n0 = blockIdx.x * 128;
  const int qd = lane >> 4, ln = lane & 15;
  const int wr = w >> 1, wc = w & 1;
  const int srow = lane >> 2;          // row within 16-row segment
  const int scol = (lane & 3) * 8;     // bf16 col offset (16B)
  f32x4 acc[4][4] = {};
  constexpr int KT = KDIM / 32;
  for (int kt = 0; kt < KT; ++kt) {
    __syncthreads();
#pragma unroll
    for (int i = 0; i < 2; ++i) {
      int seg = w * 2 + i;
      const u16* ga = A + (size_t)(m0 + seg * 16 + srow) * KDIM + kt * 32 + scol;
      gl2lds16(ga, (char*)a_sm + seg * 1024);
      const u16* gb = BT + (size_t)(n0 + seg * 16 + srow) * KDIM + kt * 32 + scol;
      gl2lds16(gb, (char*)b_sm + seg * 1024);
    }
    __syncthreads();   // drains vmcnt, tiles visible
    bf16x8 af[4], bf[4];
#pragma unroll
    for (int t = 0; t < 4; ++t) {
      af[t] = *(const bf16x8*)&a_sm[(wr * 64 + t * 16 + ln) * 32 + qd * 8];
      bf[t] = *(const bf16x8*)&b_sm[(wc * 64 + t * 16 + ln) * 32 + qd * 8];
    }
#pragma unroll
    for (int mt = 0; mt < 4; ++mt)
#pragma unroll
      for (int nt = 0; nt < 4; ++nt)
        acc[mt][nt] = mfma16(af[mt], bf[nt], acc[mt][nt]);
  }
#pragma unroll
  for (int mt = 0; mt < 4; ++mt) {
#pragma unroll
    for (int i = 0; i < 4; ++i) {
      int row = m0 + wr * 64 + mt * 16 + qd * 4 + i;
#pragma unroll
      for (int nt = 0; nt < 4; ++nt) {
        int col = n0 + wc * 64 + nt * 16 + ln;
        if ((NREAL % 128 == 0) || col < NREAL) {
          float v = acc[mt][nt][i] + bias[col];
          if (OUT_BF16) ((u16*)Cv)[(size_t)row * NSTRIDE + col] = f2b(v);
          else          ((float*)Cv)[(size_t)row * NSTRIDE + col] = v;
        }
      }
    }
  }
}

// ---- fused attention per (b,h): S=qk^T*scale+bias, softmax, O=P@v --------
__global__ __launch_bounds__(256) void attn_kernel(const u16* __restrict__ qkv,
                                                   const float* __restrict__ bfull,
                                                   u16* __restrict__ AO) {
  __shared__ u16 k_sm[NPAD * 32];        // K: [tok][d]            14336 B
  __shared__ u16 v_sm[28 * 128 * 8];     // V swizzled B-frag      57344 B
  __shared__ u16 p_sm[4][16 * NPAD];     // per-wave P row-tiles   28672 B
  int bh = blockIdx.x;
  int b = bh / NHEAD, h = bh - b * NHEAD;
  const u16* base = qkv + (size_t)b * NSEQ * HOUT + h * 192;
  int tid = threadIdx.x;
  // stage K (196x32) as uint4
  for (int u = tid; u < 784; u += 256) {
    int tok = u >> 2, d8 = (u & 3) * 8;
    *(uint4*)&k_sm[tok * 32 + d8] = *(const uint4*)(base + (size_t)tok * HOUT + 32 + d8);
  }
  for (int u = tid; u < 112; u += 256) { // zero pad rows 196..223
    int tok = 196 + (u >> 2), d8 = (u & 3) * 8;
    uint4 z = {0, 0, 0, 0};
    *(uint4*)&k_sm[tok * 32 + d8] = z;
  }
  // stage V swizzled: v_sm[((tok>>3)*128 + d)*8 + (tok&7)]
  for (int u = tid; u < 3136; u += 256) {
    int tok = u >> 4, d8 = (u & 15) * 8;
    union { uint4 q; u16 hh[8]; } uu;
    uu.q = *(const uint4*)(base + (size_t)tok * HOUT + 64 + d8);
    int kg = tok >> 3, j = tok & 7;
    u16* dv = &v_sm[(kg * 128 + d8) * 8 + j];
#pragma unroll
    for (int e = 0; e < 8; ++e) dv[e * 8] = uu.hh[e];
  }
  for (int u = tid; u < 3584; u += 256) { // zero pad toks 196..223
    int tok = 196 + (u >> 7), d = u & 127;
    v_sm[((tok >> 3) * 128 + d) * 8 + (tok & 7)] = 0;
  }
  __syncthreads();
  int wv = tid >> 6, lane = tid & 63;
  int qd = lane >> 4, ln = lane & 15;
  const float* bh_bias = bfull + (size_t)h * (NSEQ * NSEQ);
  u16* pw = p_sm[wv];
  for (int mt = wv; mt < 13; mt += 4) {
    int tokc = mt * 16 + ln; if (tokc > 195) tokc = 195;   // clamp pad rows
    bf16x8 qf = *(const bf16x8*)(base + (size_t)tokc * HOUT + qd * 8);
    f32x4 s[14];
#pragma unroll
    for (int nt = 0; nt < 14; ++nt) {
      bf16x8 kf = *(const bf16x8*)&k_sm[(nt * 16 + ln) * 32 + qd * 8];
      f32x4 z = {0.f, 0.f, 0.f, 0.f};
      s[nt] = mfma16(qf, kf, z);
    }
    int mbase = mt * 16 + qd * 4;
#pragma unroll
    for (int nt = 0; nt < 14; ++nt) {
      int n = nt * 16 + ln;
      bool nv = (n < NSEQ);
#pragma unroll
      for (int i = 0; i < 4; ++i) {
        if (nv) {
          int m = mbase + i; int mc = m > 195 ? 195 : m;
          s[nt][i] = s[nt][i] * SCALE + bh_bias[mc * NSEQ + n];
        } else s[nt][i] = -1e30f;
      }
    }
    // row softmax (row m = mbase+i lives in 16 lanes sharing qd)
#pragma unroll
    for (int i = 0; i < 4; ++i) {
      float mx = -1e30f;
#pragma unroll
      for (int nt = 0; nt < 14; ++nt) mx = fmaxf(mx, s[nt][i]);
#pragma unroll
      for (int o = 8; o >= 1; o >>= 1) mx = fmaxf(mx, __shfl_xor(mx, o, 64));
      float sum = 0.f;
#pragma unroll
      for (int nt = 0; nt < 14; ++nt) { float e = __expf(s[nt][i] - mx); s[nt][i] = e; sum += e; }
#pragma unroll
      for (int o = 8; o >= 1; o >>= 1) sum += __shfl_xor(sum, o, 64);
      float inv = 1.f / sum;
#pragma unroll
      for (int nt = 0; nt < 14; ++nt)
        pw[(qd * 4 + i) * NPAD + nt * 16 + ln] = f2b(s[nt][i] * inv);
    }
    __builtin_amdgcn_fence(__ATOMIC_SEQ_CST, "wavefront"); // order P write->read
    f32x4 o8[8] = {};
#pragma unroll
    for (int kc = 0; kc < 7; ++kc) {
      bf16x8 pf = *(const bf16x8*)&pw[ln * NPAD + kc * 32 + qd * 8];
#pragma unroll
      for (int vt = 0; vt < 8; ++vt) {
        bf16x8 vf = *(const bf16x8*)&v_sm[((kc * 4 + qd) * 128 + vt * 16 + ln) * 8];
        o8[vt] = mfma16(pf, vf, o8[vt]);
      }
    }
    __builtin_amdgcn_fence(__ATOMIC_SEQ_CST, "wavefront"); // order read->next write
#pragma unroll
    for (int i = 0; i < 4; ++i) {
      int tok = mbase + i;
      if (tok < NSEQ) {
        u16* dst = AO + ((size_t)b * NSEQ + tok) * DHC + h * 128 + ln;
#pragma unroll
        for (int vt = 0; vt < 8; ++vt) dst[vt * 16] = f2b(o8[vt][i]);
      }
    }
  }
}

// ---- launch --------------------------------------------------------------
extern "C" void kernel_launch(void* const* d_in, const int* in_sizes, int n_in,
                              void* d_out, int out_size, void* d_ws, size_t ws_size,
                              hipStream_t stream) {
  const float* x     = (const float*)d_in[0];
  const float* lnw   = (const float*)d_in[1];
  const float* lnb   = (const float*)d_in[2];
  const float* wqkv  = (const float*)d_in[3];
  const float* bqkv  = (const float*)d_in[4];
  const float* wproj = (const float*)d_in[5];
  const float* bproj = (const float*)d_in[6];
  const float* abias = (const float*)d_in[7];
  const int*   bidx  = (const int*)d_in[8];
  float* out = (float*)d_out;
  char* ws = (char*)d_ws;

  // --- fixed small buffers (9,696,384 B) ---
  u16*   wqkvT  = (u16*)(ws);                    // 3456*576*2 = 3,981,312
  u16*   wprojT = (u16*)(ws + 3981312);          // 640*2304*2 = 2,949,120
  float* bfull  = (float*)(ws + 6930432);        // 18*196*196*4 = 2,765,952
  char*  dyn    = ws + 9696384;

  // --- adaptive chunking over batch: per-token scratch = 12,672 B ---
  // NC in {1,2,4,8}; tokens per chunk (256/NC)*196 divisible by 128 for all.
  int NC = 1;
  while (NC < 8 &&
         (size_t)9696384 + (size_t)(TOKENS / NC) * 12672 > ws_size) NC *= 2;
  const int tokens_c = TOKENS / NC;              // 50176 / NC
  const int batch_c  = 256 / NC;
  u16* xn   = (u16*)(dyn);
  u16* qkvb = (u16*)(dyn + (size_t)tokens_c * 1152);
  u16* AO   = (u16*)(dyn + (size_t)tokens_c * (1152 + 6912));

  int off_stride = in_sizes[7] / NHEAD;          // offset_size (=196 for 14x14)

  transpose_cast<<<7776, 256, 0, stream>>>(wqkv, wqkvT, 576, 3456, 3456);
  transpose_cast<<<5760, 256, 0, stream>>>(wproj, wprojT, 2304, 576, 640);
  bias_expand<<<2702, 256, 0, stream>>>(abias, bidx, bfull, off_stride);

  for (int c = 0; c < NC; ++c) {
    const int tok0 = c * tokens_c;
    ln_kernel<<<tokens_c / 4, 256, 0, stream>>>(x + (size_t)tok0 * DIMC, lnw, lnb, xn);
    gemm_tn<576, 3456, 3456, true>
        <<<dim3(27, tokens_c / 128), 256, 0, stream>>>(xn, wqkvT, bqkv, qkvb);
    attn_kernel<<<batch_c * NHEAD, 256, 0, stream>>>(qkvb, bfull, AO);
    gemm_tn<2304, 576, 576, false>
        <<<dim3(5, tokens_c / 128), 256, 0, stream>>>(AO, wprojT, bproj,
                                                      out + (size_t)tok0 * DIMC);
  }
}

// Round 3
// 1143.783 us; speedup vs baseline: 1.1688x; 1.1688x over previous
//
#include <hip/hip_runtime.h>
#include <cstdint>

typedef unsigned short u16;
typedef unsigned int   u32;
typedef __bf16 bf16x8 __attribute__((ext_vector_type(8)));
typedef float  f32x4  __attribute__((ext_vector_type(4)));

#define TOKENS 50176
#define DIMC   576
#define HOUT   3456
#define DHC    2304
#define NHEAD  18
#define NSEQ   196
#define NPAD   224
#define VDP    129            // V d-stride pad: kg stride = 129*8 u16 = 2064 B = bank+4
#define PST    232            // P row stride (u16): 16B-aligned, breaks qd degeneracy
#define SCALE  0.17677669529663687f

// ---- helpers -------------------------------------------------------------
__device__ __forceinline__ u16 f2b(float f) {            // fp32 -> bf16 RNE
  union { float f; u32 u; } v; v.f = f;
  u32 u = v.u;
  return (u16)((u + 0x7fffu + ((u >> 16) & 1u)) >> 16);
}

__device__ __forceinline__ f32x4 mfma16(bf16x8 a, bf16x8 b, f32x4 c) {
  return __builtin_amdgcn_mfma_f32_16x16x32_bf16(a, b, c, 0, 0, 0);
}

typedef const __attribute__((address_space(1))) char gas_char;
typedef __attribute__((address_space(3))) char las_char;
// async global->LDS, 16B/lane; LDS dest = wave-uniform base + lane*16
__device__ __forceinline__ void gl2lds16(const void* g, void* l) {
  __builtin_amdgcn_global_load_lds((gas_char*)(uintptr_t)g,
                                   (las_char*)(u32)(uintptr_t)l, 16, 0, 0);
}

// ---- LayerNorm -> bf16 ---------------------------------------------------
__global__ __launch_bounds__(256) void ln_kernel(const float* __restrict__ x,
                                                 const float* __restrict__ w,
                                                 const float* __restrict__ bsh,
                                                 u16* __restrict__ xn) {
  int lane = threadIdx.x & 63;
  int tok  = blockIdx.x * 4 + (threadIdx.x >> 6);
  const float* xr = x + (size_t)tok * DIMC;
  float v[9]; float s = 0.f;
#pragma unroll
  for (int i = 0; i < 9; ++i) { v[i] = xr[lane + 64 * i]; s += v[i]; }
#pragma unroll
  for (int o = 32; o >= 1; o >>= 1) s += __shfl_xor(s, o, 64);
  float mu = s * (1.f / 576.f);
  float var = 0.f;
#pragma unroll
  for (int i = 0; i < 9; ++i) { float d = v[i] - mu; var += d * d; }
#pragma unroll
  for (int o = 32; o >= 1; o >>= 1) var += __shfl_xor(var, o, 64);
  float rs = rsqrtf(var * (1.f / 576.f) + 1e-5f);
  u16* xo = xn + (size_t)tok * DIMC;
#pragma unroll
  for (int i = 0; i < 9; ++i) {
    int c = lane + 64 * i;
    xo[c] = f2b((v[i] - mu) * rs * w[c] + bsh[c]);
  }
}

// ---- cast + transpose weights: src KxNn (fp32) -> dst Npad x K (bf16) ----
__global__ void transpose_cast(const float* __restrict__ src, u16* __restrict__ dst,
                               int K, int Nn, int Npad) {
  int idx = blockIdx.x * 256 + threadIdx.x;
  if (idx >= K * Npad) return;
  int k = idx / Npad, n = idx - k * Npad;
  dst[(size_t)n * K + k] = (n < Nn) ? f2b(src[(size_t)k * Nn + n]) : (u16)0;
}

// ---- expand attention bias gather: bfull[h][m][n] ------------------------
__global__ void bias_expand(const float* __restrict__ ab, const int* __restrict__ idxs,
                            float* __restrict__ bf, int off_stride) {
  int i = blockIdx.x * 256 + threadIdx.x;
  if (i >= NHEAD * NSEQ * NSEQ) return;
  int h = i / (NSEQ * NSEQ), mn = i - h * (NSEQ * NSEQ);
  bf[i] = ab[h * off_stride + idxs[mn]];
}

// ---- 128x128-tile bf16 MFMA GEMM, A (MxK) row-major, BT (NxK) row-major --
template <int KDIM, int NSTRIDE, int NREAL, bool OUT_BF16>
__global__ __launch_bounds__(256) void gemm_tn(const u16* __restrict__ A,
                                               const u16* __restrict__ BT,
                                               const float* __restrict__ bias,
                                               void* __restrict__ Cv) {
  __shared__ u16 a_sm[128 * 32];
  __shared__ u16 b_sm[128 * 32];
  const int tid = threadIdx.x;
  const int w = tid >> 6, lane = tid & 63;
  const int m0 = blockIdx.y * 128, n0 = blockIdx.x * 128;
  const int qd = lane >> 4, ln = lane & 15;
  const int wr = w >> 1, wc = w & 1;
  const int srow = lane >> 2;          // row within 16-row segment
  const int scol = (lane & 3) * 8;     // bf16 col offset (16B)
  f32x4 acc[4][4] = {};
  constexpr int KT = KDIM / 32;
  for (int kt = 0; kt < KT; ++kt) {
    __syncthreads();
#pragma unroll
    for (int i = 0; i < 2; ++i) {
      int seg = w * 2 + i;
      const u16* ga = A + (size_t)(m0 + seg * 16 + srow) * KDIM + kt * 32 + scol;
      gl2lds16(ga, (char*)a_sm + seg * 1024);
      const u16* gb = BT + (size_t)(n0 + seg * 16 + srow) * KDIM + kt * 32 + scol;
      gl2lds16(gb, (char*)b_sm + seg * 1024);
    }
    __syncthreads();   // drains vmcnt, tiles visible
    bf16x8 af[4], bf[4];
#pragma unroll
    for (int t = 0; t < 4; ++t) {
      af[t] = *(const bf16x8*)&a_sm[(wr * 64 + t * 16 + ln) * 32 + qd * 8];
      bf[t] = *(const bf16x8*)&b_sm[(wc * 64 + t * 16 + ln) * 32 + qd * 8];
    }
#pragma unroll
    for (int mt = 0; mt < 4; ++mt)
#pragma unroll
      for (int nt = 0; nt < 4; ++nt)
        acc[mt][nt] = mfma16(af[mt], bf[nt], acc[mt][nt]);
  }
#pragma unroll
  for (int mt = 0; mt < 4; ++mt) {
#pragma unroll
    for (int i = 0; i < 4; ++i) {
      int row = m0 + wr * 64 + mt * 16 + qd * 4 + i;
#pragma unroll
      for (int nt = 0; nt < 4; ++nt) {
        int col = n0 + wc * 64 + nt * 16 + ln;
        if ((NREAL % 128 == 0) || col < NREAL) {
          float v = acc[mt][nt][i] + bias[col];
          if (OUT_BF16) ((u16*)Cv)[(size_t)row * NSTRIDE + col] = f2b(v);
          else          ((float*)Cv)[(size_t)row * NSTRIDE + col] = v;
        }
      }
    }
  }
}

// ---- fused attention per (b,h): S=qk^T*scale+bias, softmax, O=P@v --------
// 512 threads = 8 waves; 1 block/CU (131 KB LDS) -> 8 waves/CU latency hiding.
__global__ __launch_bounds__(512) void attn_kernel(const u16* __restrict__ qkv,
                                                   const float* __restrict__ bfull,
                                                   u16* __restrict__ AO) {
  __shared__ u16 k_sm[NPAD * 32];         // K: [tok][d]              14336 B
  __shared__ u16 v_sm[28 * VDP * 8];      // V swizzled, d-padded     57792 B
  __shared__ u16 p_sm[8][16 * PST];       // per-wave P row-tiles     59392 B
  int bh = blockIdx.x;
  int b = bh / NHEAD, h = bh - b * NHEAD;
  const u16* base = qkv + (size_t)b * NSEQ * HOUT + h * 192;
  int tid = threadIdx.x;
  // stage K (196x32) as uint4
  for (int u = tid; u < 784; u += 512) {
    int tok = u >> 2, d8 = (u & 3) * 8;
    *(uint4*)&k_sm[tok * 32 + d8] = *(const uint4*)(base + (size_t)tok * HOUT + 32 + d8);
  }
  for (int u = tid; u < 112; u += 512) { // zero pad rows 196..223
    int tok = 196 + (u >> 2), d8 = (u & 3) * 8;
    uint4 z = {0, 0, 0, 0};
    *(uint4*)&k_sm[tok * 32 + d8] = z;
  }
  // stage V swizzled: v_sm[(kg*VDP + d)*8 + j], kg=tok>>3, j=tok&7.
  // unit = d8blk*196 + tok -> consecutive lanes take consecutive tok:
  // 8 j-lanes hit 4 consecutive banks (free), kg strata at bank+4 -> no conflict.
  for (int u = tid; u < 3136; u += 512) {
    int d8b = u / 196, tok = u - d8b * 196;
    union { uint4 q; u16 hh[8]; } uu;
    uu.q = *(const uint4*)(base + (size_t)tok * HOUT + 64 + d8b * 8);
    int kg = tok >> 3, j = tok & 7;
    u16* dv = &v_sm[(kg * VDP + d8b * 8) * 8 + j];
#pragma unroll
    for (int e = 0; e < 8; ++e) dv[e * 8] = uu.hh[e];
  }
  for (int u = tid; u < 448; u += 512) { // zero pad toks 196..223
    int d8b = u / 28, tokp = 196 + (u - d8b * 28);
    int kg = tokp >> 3, j = tokp & 7;
    u16* dv = &v_sm[(kg * VDP + d8b * 8) * 8 + j];
#pragma unroll
    for (int e = 0; e < 8; ++e) dv[e * 8] = 0;
  }
  __syncthreads();
  int wv = tid >> 6, lane = tid & 63;
  int qd = lane >> 4, ln = lane & 15;
  const float* bh_bias = bfull + (size_t)h * (NSEQ * NSEQ);
  u16* pw = p_sm[wv];
  for (int mt = wv; mt < 13; mt += 8) {
    int tokc = mt * 16 + ln; if (tokc > 195) tokc = 195;   // clamp pad rows
    bf16x8 qf = *(const bf16x8*)(base + (size_t)tokc * HOUT + qd * 8);
    f32x4 s[14];
#pragma unroll
    for (int nt = 0; nt < 14; ++nt) {
      bf16x8 kf = *(const bf16x8*)&k_sm[(nt * 16 + ln) * 32 + qd * 8];
      f32x4 z = {0.f, 0.f, 0.f, 0.f};
      s[nt] = mfma16(qf, kf, z);
    }
    int mbase = mt * 16 + qd * 4;
#pragma unroll
    for (int nt = 0; nt < 14; ++nt) {
      int n = nt * 16 + ln;
      bool nv = (n < NSEQ);
#pragma unroll
      for (int i = 0; i < 4; ++i) {
        if (nv) {
          int m = mbase + i; int mc = m > 195 ? 195 : m;
          s[nt][i] = s[nt][i] * SCALE + bh_bias[mc * NSEQ + n];
        } else s[nt][i] = -1e30f;
      }
    }
    // row softmax (row m = mbase+i lives in 16 lanes sharing qd)
#pragma unroll
    for (int i = 0; i < 4; ++i) {
      float mx = -1e30f;
#pragma unroll
      for (int nt = 0; nt < 14; ++nt) mx = fmaxf(mx, s[nt][i]);
#pragma unroll
      for (int o = 8; o >= 1; o >>= 1) mx = fmaxf(mx, __shfl_xor(mx, o, 64));
      float sum = 0.f;
#pragma unroll
      for (int nt = 0; nt < 14; ++nt) { float e = __expf(s[nt][i] - mx); s[nt][i] = e; sum += e; }
#pragma unroll
      for (int o = 8; o >= 1; o >>= 1) sum += __shfl_xor(sum, o, 64);
      float inv = 1.f / sum;
#pragma unroll
      for (int nt = 0; nt < 14; ++nt)
        pw[(qd * 4 + i) * PST + nt * 16 + ln] = f2b(s[nt][i] * inv);
    }
    __builtin_amdgcn_fence(__ATOMIC_SEQ_CST, "wavefront"); // order P write->read
    f32x4 o8[8] = {};
#pragma unroll
    for (int kc = 0; kc < 7; ++kc) {
      bf16x8 pf = *(const bf16x8*)&pw[ln * PST + kc * 32 + qd * 8];
#pragma unroll
      for (int vt = 0; vt < 8; ++vt) {
        bf16x8 vf = *(const bf16x8*)&v_sm[((kc * 4 + qd) * VDP + vt * 16 + ln) * 8];
        o8[vt] = mfma16(pf, vf, o8[vt]);
      }
    }
    __builtin_amdgcn_fence(__ATOMIC_SEQ_CST, "wavefront"); // order read->next write
#pragma unroll
    for (int i = 0; i < 4; ++i) {
      int tok = mbase + i;
      if (tok < NSEQ) {
        u16* dst = AO + ((size_t)b * NSEQ + tok) * DHC + h * 128 + ln;
#pragma unroll
        for (int vt = 0; vt < 8; ++vt) dst[vt * 16] = f2b(o8[vt][i]);
      }
    }
  }
}

// ---- launch --------------------------------------------------------------
extern "C" void kernel_launch(void* const* d_in, const int* in_sizes, int n_in,
                              void* d_out, int out_size, void* d_ws, size_t ws_size,
                              hipStream_t stream) {
  const float* x     = (const float*)d_in[0];
  const float* lnw   = (const float*)d_in[1];
  const float* lnb   = (const float*)d_in[2];
  const float* wqkv  = (const float*)d_in[3];
  const float* bqkv  = (const float*)d_in[4];
  const float* wproj = (const float*)d_in[5];
  const float* bproj = (const float*)d_in[6];
  const float* abias = (const float*)d_in[7];
  const int*   bidx  = (const int*)d_in[8];
  float* out = (float*)d_out;
  char* ws = (char*)d_ws;

  // --- fixed small buffers (9,696,384 B) ---
  u16*   wqkvT  = (u16*)(ws);                    // 3456*576*2 = 3,981,312
  u16*   wprojT = (u16*)(ws + 3981312);          // 640*2304*2 = 2,949,120
  float* bfull  = (float*)(ws + 6930432);        // 18*196*196*4 = 2,765,952
  char*  dyn    = ws + 9696384;

  // --- adaptive chunking over batch: per-token scratch = 12,672 B ---
  int NC = 1;
  while (NC < 8 &&
         (size_t)9696384 + (size_t)(TOKENS / NC) * 12672 > ws_size) NC *= 2;
  const int tokens_c = TOKENS / NC;              // 50176 / NC
  const int batch_c  = 256 / NC;
  u16* xn   = (u16*)(dyn);
  u16* qkvb = (u16*)(dyn + (size_t)tokens_c * 1152);
  u16* AO   = (u16*)(dyn + (size_t)tokens_c * (1152 + 6912));

  int off_stride = in_sizes[7] / NHEAD;          // offset_size (=196 for 14x14)

  transpose_cast<<<7776, 256, 0, stream>>>(wqkv, wqkvT, 576, 3456, 3456);
  transpose_cast<<<5760, 256, 0, stream>>>(wproj, wprojT, 2304, 576, 640);
  bias_expand<<<2702, 256, 0, stream>>>(abias, bidx, bfull, off_stride);

  for (int c = 0; c < NC; ++c) {
    const int tok0 = c * tokens_c;
    ln_kernel<<<tokens_c / 4, 256, 0, stream>>>(x + (size_t)tok0 * DIMC, lnw, lnb, xn);
    gemm_tn<576, 3456, 3456, true>
        <<<dim3(27, tokens_c / 128), 256, 0, stream>>>(xn, wqkvT, bqkv, qkvb);
    attn_kernel<<<batch_c * NHEAD, 512, 0, stream>>>(qkvb, bfull, AO);
    gemm_tn<2304, 576, 576, false>
        <<<dim3(5, tokens_c / 128), 256, 0, stream>>>(AO, wprojT, bproj,
                                                      out + (size_t)tok0 * DIMC);
  }
}

// Round 4
// 1063.657 us; speedup vs baseline: 1.2569x; 1.0753x over previous
//
#include <hip/hip_runtime.h>
#include <cstdint>

typedef unsigned short u16;
typedef unsigned int   u32;
typedef __bf16 bf16x8 __attribute__((ext_vector_type(8)));
typedef float  f32x4  __attribute__((ext_vector_type(4)));

#define TOKENS 50176
#define DIMC   576
#define HOUT   3456
#define DHC    2304
#define NHEAD  18
#define NSEQ   196
#define NPAD   224
#define VDP    129            // V d-stride pad: kg stride = 129*8 u16 = 2064 B = bank+4
#define PST    232            // P row stride (u16): 16B-aligned, breaks qd degeneracy
#define SCALE  0.17677669529663687f

// ---- helpers -------------------------------------------------------------
__device__ __forceinline__ u16 f2b(float f) {            // fp32 -> bf16 RNE
  union { float f; u32 u; } v; v.f = f;
  u32 u = v.u;
  return (u16)((u + 0x7fffu + ((u >> 16) & 1u)) >> 16);
}

__device__ __forceinline__ f32x4 mfma16(bf16x8 a, bf16x8 b, f32x4 c) {
  return __builtin_amdgcn_mfma_f32_16x16x32_bf16(a, b, c, 0, 0, 0);
}

typedef const __attribute__((address_space(1))) char gas_char;
typedef __attribute__((address_space(3))) char las_char;
// async global->LDS, 16B/lane; LDS dest = wave-uniform base + lane*16
__device__ __forceinline__ void gl2lds16(const void* g, void* l) {
  __builtin_amdgcn_global_load_lds((gas_char*)(uintptr_t)g,
                                   (las_char*)(u32)(uintptr_t)l, 16, 0, 0);
}

// ---- LayerNorm -> bf16 ---------------------------------------------------
__global__ __launch_bounds__(256) void ln_kernel(const float* __restrict__ x,
                                                 const float* __restrict__ w,
                                                 const float* __restrict__ bsh,
                                                 u16* __restrict__ xn) {
  int lane = threadIdx.x & 63;
  int tok  = blockIdx.x * 4 + (threadIdx.x >> 6);
  const float* xr = x + (size_t)tok * DIMC;
  float v[9]; float s = 0.f;
#pragma unroll
  for (int i = 0; i < 9; ++i) { v[i] = xr[lane + 64 * i]; s += v[i]; }
#pragma unroll
  for (int o = 32; o >= 1; o >>= 1) s += __shfl_xor(s, o, 64);
  float mu = s * (1.f / 576.f);
  float var = 0.f;
#pragma unroll
  for (int i = 0; i < 9; ++i) { float d = v[i] - mu; var += d * d; }
#pragma unroll
  for (int o = 32; o >= 1; o >>= 1) var += __shfl_xor(var, o, 64);
  float rs = rsqrtf(var * (1.f / 576.f) + 1e-5f);
  u16* xo = xn + (size_t)tok * DIMC;
#pragma unroll
  for (int i = 0; i < 9; ++i) {
    int c = lane + 64 * i;
    xo[c] = f2b((v[i] - mu) * rs * w[c] + bsh[c]);
  }
}

// ---- cast + transpose weights: src KxNn (fp32) -> dst Npad x K (bf16) ----
__global__ void transpose_cast(const float* __restrict__ src, u16* __restrict__ dst,
                               int K, int Nn, int Npad) {
  int idx = blockIdx.x * 256 + threadIdx.x;
  if (idx >= K * Npad) return;
  int k = idx / Npad, n = idx - k * Npad;
  dst[(size_t)n * K + k] = (n < Nn) ? f2b(src[(size_t)k * Nn + n]) : (u16)0;
}

// ---- expand attention bias gather: bfull[h][m][n] ------------------------
__global__ void bias_expand(const float* __restrict__ ab, const int* __restrict__ idxs,
                            float* __restrict__ bf, int off_stride) {
  int i = blockIdx.x * 256 + threadIdx.x;
  if (i >= NHEAD * NSEQ * NSEQ) return;
  int h = i / (NSEQ * NSEQ), mn = i - h * (NSEQ * NSEQ);
  bf[i] = ab[h * off_stride + idxs[mn]];
}

// ---- 128x128-tile bf16 MFMA GEMM, BK=64, XOR-swizzled LDS ---------------
// A (MxK) row-major, BT (NxK) row-major. LDS row = 64 u16 = 128 B = exact
// bank wrap; global chunk (c ^ row&7) stored at LDS chunk c -> fragment
// reads hit all 32 banks 2-way (free, m136).
template <int KDIM, int NSTRIDE, int NREAL, bool OUT_BF16>
__global__ __launch_bounds__(256, 3) void gemm_tn(const u16* __restrict__ A,
                                                  const u16* __restrict__ BT,
                                                  const float* __restrict__ bias,
                                                  void* __restrict__ Cv) {
  __shared__ u16 a_sm[128 * 64];   // 16 KB
  __shared__ u16 b_sm[128 * 64];   // 16 KB
  const int tid = threadIdx.x;
  const int w = tid >> 6, lane = tid & 63;
  const int m0 = blockIdx.y * 128, n0 = blockIdx.x * 128;
  const int qd = lane >> 4, ln = lane & 15;
  const int wr = w >> 1, wc = w & 1;
  const int srow = lane >> 3;                 // row within 8-row segment
  const int scol = ((lane & 7) ^ srow) * 8;   // XOR-swizzled source chunk
  f32x4 acc[4][4] = {};
  constexpr int KT = KDIM / 64;
  for (int kt = 0; kt < KT; ++kt) {
    __syncthreads();
#pragma unroll
    for (int i = 0; i < 4; ++i) {
      int seg = w * 4 + i;                    // 16 segs of 8 rows each
      const u16* ga = A + (size_t)(m0 + seg * 8 + srow) * KDIM + kt * 64 + scol;
      gl2lds16(ga, (char*)a_sm + seg * 1024);
      const u16* gb = BT + (size_t)(n0 + seg * 8 + srow) * KDIM + kt * 64 + scol;
      gl2lds16(gb, (char*)b_sm + seg * 1024);
    }
    __syncthreads();   // drains vmcnt, tiles visible
#pragma unroll 1
    for (int kk = 0; kk < 2; ++kk) {
      const int xc = ((kk * 4 + qd) ^ (ln & 7)) * 8;
      bf16x8 af[4], bff[4];
#pragma unroll
      for (int t = 0; t < 4; ++t) {
        af[t]  = *(const bf16x8*)&a_sm[(wr * 64 + t * 16 + ln) * 64 + xc];
        bff[t] = *(const bf16x8*)&b_sm[(wc * 64 + t * 16 + ln) * 64 + xc];
      }
#pragma unroll
      for (int mt = 0; mt < 4; ++mt)
#pragma unroll
        for (int nt = 0; nt < 4; ++nt)
          acc[mt][nt] = mfma16(af[mt], bff[nt], acc[mt][nt]);
    }
  }
#pragma unroll
  for (int mt = 0; mt < 4; ++mt) {
#pragma unroll
    for (int i = 0; i < 4; ++i) {
      int row = m0 + wr * 64 + mt * 16 + qd * 4 + i;
#pragma unroll
      for (int nt = 0; nt < 4; ++nt) {
        int col = n0 + wc * 64 + nt * 16 + ln;
        if ((NREAL % 128 == 0) || col < NREAL) {
          float v = acc[mt][nt][i] + bias[col];
          if (OUT_BF16) ((u16*)Cv)[(size_t)row * NSTRIDE + col] = f2b(v);
          else          ((float*)Cv)[(size_t)row * NSTRIDE + col] = v;
        }
      }
    }
  }
}

// ---- fused attention per (b,h): S=qk^T*scale+bias, softmax, O=P@v --------
// 512 threads = 8 waves; 1 block/CU (131 KB LDS) -> 8 waves/CU latency hiding.
__global__ __launch_bounds__(512) void attn_kernel(const u16* __restrict__ qkv,
                                                   const float* __restrict__ bfull,
                                                   u16* __restrict__ AO) {
  __shared__ u16 k_sm[NPAD * 32];         // K: [tok][d]              14336 B
  __shared__ u16 v_sm[28 * VDP * 8];      // V swizzled, d-padded     57792 B
  __shared__ u16 p_sm[8][16 * PST];       // per-wave P row-tiles     59392 B
  int bh = blockIdx.x;
  int b = bh / NHEAD, h = bh - b * NHEAD;
  const u16* base = qkv + (size_t)b * NSEQ * HOUT + h * 192;
  int tid = threadIdx.x;
  // stage K (196x32) as uint4
  for (int u = tid; u < 784; u += 512) {
    int tok = u >> 2, d8 = (u & 3) * 8;
    *(uint4*)&k_sm[tok * 32 + d8] = *(const uint4*)(base + (size_t)tok * HOUT + 32 + d8);
  }
  for (int u = tid; u < 112; u += 512) { // zero pad rows 196..223
    int tok = 196 + (u >> 2), d8 = (u & 3) * 8;
    uint4 z = {0, 0, 0, 0};
    *(uint4*)&k_sm[tok * 32 + d8] = z;
  }
  // stage V swizzled: v_sm[(kg*VDP + d)*8 + j], kg=tok>>3, j=tok&7.
  for (int u = tid; u < 3136; u += 512) {
    int d8b = u / 196, tok = u - d8b * 196;
    union { uint4 q; u16 hh[8]; } uu;
    uu.q = *(const uint4*)(base + (size_t)tok * HOUT + 64 + d8b * 8);
    int kg = tok >> 3, j = tok & 7;
    u16* dv = &v_sm[(kg * VDP + d8b * 8) * 8 + j];
#pragma unroll
    for (int e = 0; e < 8; ++e) dv[e * 8] = uu.hh[e];
  }
  for (int u = tid; u < 448; u += 512) { // zero pad toks 196..223
    int d8b = u / 28, tokp = 196 + (u - d8b * 28);
    int kg = tokp >> 3, j = tokp & 7;
    u16* dv = &v_sm[(kg * VDP + d8b * 8) * 8 + j];
#pragma unroll
    for (int e = 0; e < 8; ++e) dv[e * 8] = 0;
  }
  __syncthreads();
  int wv = tid >> 6, lane = tid & 63;
  int qd = lane >> 4, ln = lane & 15;
  const float* bh_bias = bfull + (size_t)h * (NSEQ * NSEQ);
  u16* pw = p_sm[wv];
  for (int mt = wv; mt < 13; mt += 8) {
    int tokc = mt * 16 + ln; if (tokc > 195) tokc = 195;   // clamp pad rows
    bf16x8 qf = *(const bf16x8*)(base + (size_t)tokc * HOUT + qd * 8);
    f32x4 s[14];
#pragma unroll
    for (int nt = 0; nt < 14; ++nt) {
      bf16x8 kf = *(const bf16x8*)&k_sm[(nt * 16 + ln) * 32 + qd * 8];
      f32x4 z = {0.f, 0.f, 0.f, 0.f};
      s[nt] = mfma16(qf, kf, z);
    }
    int mbase = mt * 16 + qd * 4;
#pragma unroll
    for (int nt = 0; nt < 14; ++nt) {
      int n = nt * 16 + ln;
      bool nv = (n < NSEQ);
#pragma unroll
      for (int i = 0; i < 4; ++i) {
        if (nv) {
          int m = mbase + i; int mc = m > 195 ? 195 : m;
          s[nt][i] = s[nt][i] * SCALE + bh_bias[mc * NSEQ + n];
        } else s[nt][i] = -1e30f;
      }
    }
    // row softmax (row m = mbase+i lives in 16 lanes sharing qd)
#pragma unroll
    for (int i = 0; i < 4; ++i) {
      float mx = -1e30f;
#pragma unroll
      for (int nt = 0; nt < 14; ++nt) mx = fmaxf(mx, s[nt][i]);
#pragma unroll
      for (int o = 8; o >= 1; o >>= 1) mx = fmaxf(mx, __shfl_xor(mx, o, 64));
      float sum = 0.f;
#pragma unroll
      for (int nt = 0; nt < 14; ++nt) { float e = __expf(s[nt][i] - mx); s[nt][i] = e; sum += e; }
#pragma unroll
      for (int o = 8; o >= 1; o >>= 1) sum += __shfl_xor(sum, o, 64);
      float inv = 1.f / sum;
#pragma unroll
      for (int nt = 0; nt < 14; ++nt)
        pw[(qd * 4 + i) * PST + nt * 16 + ln] = f2b(s[nt][i] * inv);
    }
    __builtin_amdgcn_fence(__ATOMIC_SEQ_CST, "wavefront"); // order P write->read
    f32x4 o8[8] = {};
#pragma unroll
    for (int kc = 0; kc < 7; ++kc) {
      bf16x8 pf = *(const bf16x8*)&pw[ln * PST + kc * 32 + qd * 8];
#pragma unroll
      for (int vt = 0; vt < 8; ++vt) {
        bf16x8 vf = *(const bf16x8*)&v_sm[((kc * 4 + qd) * VDP + vt * 16 + ln) * 8];
        o8[vt] = mfma16(pf, vf, o8[vt]);
      }
    }
    __builtin_amdgcn_fence(__ATOMIC_SEQ_CST, "wavefront"); // order read->next write
#pragma unroll
    for (int i = 0; i < 4; ++i) {
      int tok = mbase + i;
      if (tok < NSEQ) {
        u16* dst = AO + ((size_t)b * NSEQ + tok) * DHC + h * 128 + ln;
#pragma unroll
        for (int vt = 0; vt < 8; ++vt) dst[vt * 16] = f2b(o8[vt][i]);
      }
    }
  }
}

// ---- launch --------------------------------------------------------------
extern "C" void kernel_launch(void* const* d_in, const int* in_sizes, int n_in,
                              void* d_out, int out_size, void* d_ws, size_t ws_size,
                              hipStream_t stream) {
  const float* x     = (const float*)d_in[0];
  const float* lnw   = (const float*)d_in[1];
  const float* lnb   = (const float*)d_in[2];
  const float* wqkv  = (const float*)d_in[3];
  const float* bqkv  = (const float*)d_in[4];
  const float* wproj = (const float*)d_in[5];
  const float* bproj = (const float*)d_in[6];
  const float* abias = (const float*)d_in[7];
  const int*   bidx  = (const int*)d_in[8];
  float* out = (float*)d_out;
  char* ws = (char*)d_ws;

  // --- fixed small buffers (9,696,384 B) ---
  u16*   wqkvT  = (u16*)(ws);                    // 3456*576*2 = 3,981,312
  u16*   wprojT = (u16*)(ws + 3981312);          // 640*2304*2 = 2,949,120
  float* bfull  = (float*)(ws + 6930432);        // 18*196*196*4 = 2,765,952
  char*  dyn    = ws + 9696384;

  // --- adaptive chunking over batch: per-token scratch = 12,672 B ---
  int NC = 1;
  while (NC < 8 &&
         (size_t)9696384 + (size_t)(TOKENS / NC) * 12672 > ws_size) NC *= 2;
  const int tokens_c = TOKENS / NC;              // 50176 / NC
  const int batch_c  = 256 / NC;
  u16* xn   = (u16*)(dyn);
  u16* qkvb = (u16*)(dyn + (size_t)tokens_c * 1152);
  u16* AO   = (u16*)(dyn + (size_t)tokens_c * (1152 + 6912));

  int off_stride = in_sizes[7] / NHEAD;          // offset_size (=196 for 14x14)

  transpose_cast<<<7776, 256, 0, stream>>>(wqkv, wqkvT, 576, 3456, 3456);
  transpose_cast<<<5760, 256, 0, stream>>>(wproj, wprojT, 2304, 576, 640);
  bias_expand<<<2702, 256, 0, stream>>>(abias, bidx, bfull, off_stride);

  for (int c = 0; c < NC; ++c) {
    const int tok0 = c * tokens_c;
    ln_kernel<<<tokens_c / 4, 256, 0, stream>>>(x + (size_t)tok0 * DIMC, lnw, lnb, xn);
    gemm_tn<576, 3456, 3456, true>
        <<<dim3(27, tokens_c / 128), 256, 0, stream>>>(xn, wqkvT, bqkv, qkvb);
    attn_kernel<<<batch_c * NHEAD, 512, 0, stream>>>(qkvb, bfull, AO);
    gemm_tn<2304, 576, 576, false>
        <<<dim3(5, tokens_c / 128), 256, 0, stream>>>(AO, wprojT, bproj,
                                                      out + (size_t)tok0 * DIMC);
  }
}